// Round 12
// baseline (36.725 us; speedup 1.0000x reference)
//
#include <hip/hip_runtime.h>

// Chamfer distance via MFMA (bf16 split-precision, exact products), fp32 in/out.
// B=4, N=M=8192.  d_ij = |p|^2 + |t|^2 - 2 p.t.
// A-row (target, prep-formatted): [-2th(xyz) -2tl(xyz) -2th(xyz) -2tl(xyz) t2h t2l 0 0]
// B-row (pred, built in-wave):    [ ph(xyz)   ph(xyz)   pl(xyz)   pl(xyz)  1   1  0 0]
// One mfma_f32_32x32x16_bf16 -> 32x32 of (d_ij - |p_j|^2); bf16xbf16 products are
// exact in fp32, so error ~2^-18 (validated: absmax 0.0 in rounds 9-10).
// v3: 3 kernels (merge+reduce fused via last-block ticket), register-dieted mfma
// with compile-time prefetch offsets.

typedef short s8v __attribute__((ext_vector_type(8)));
typedef float f16v __attribute__((ext_vector_type(16)));

#define NPTS 8192
#define NB 4
#define CHUNKS 8          // target chunks of 1024 (32 tiles of 32)

__device__ inline unsigned short f2bf(float f) {          // fp32 -> bf16 (RNE)
    unsigned u = __builtin_bit_cast(unsigned, f);
    unsigned r = u + 0x7FFFu + ((u >> 16) & 1u);
    return (unsigned short)(r >> 16);
}
__device__ inline float bf2f(unsigned short s) {
    unsigned u = ((unsigned)s) << 16;
    return __builtin_bit_cast(float, u);
}
__device__ inline s8v load16(const unsigned short* p) {   // 8 bf16 = 16 B
    int4 v = *(const int4*)p;
    return __builtin_bit_cast(s8v, v);
}
// fold 16 acc values + running min via v_min3 chain (8 instrs)
__device__ inline float mintree(const f16v& c, float mn) {
    float m = fminf(fminf(c[0], c[1]), c[2]);
    m = fminf(fminf(m, c[3]), c[4]);
    m = fminf(fminf(m, c[5]), c[6]);
    m = fminf(fminf(m, c[7]), c[8]);
    m = fminf(fminf(m, c[9]), c[10]);
    m = fminf(fminf(m, c[11]), c[12]);
    m = fminf(fminf(m, c[13]), c[14]);
    return fminf(fminf(m, c[15]), mn);
}

// ---- K1 prep: format both clouds as A-rows; zero the ticket ----
__global__ __launch_bounds__(256) void chamfer_prep(
    const float* __restrict__ pred, const float* __restrict__ target,
    unsigned short* __restrict__ afmt, int* __restrict__ done)
{
    if (blockIdx.x == 0 && threadIdx.x == 0) *done = 0;

    const int g = blockIdx.x * 256 + threadIdx.x;   // 0..65535
    const int c = g >> 15;
    const int rem = g & 32767;                      // b*NPTS + i
    const float* src = (c == 0 ? pred : target) + (size_t)rem * 3;
    const float x = src[0], y = src[1], z = src[2];

    const unsigned short hx = f2bf(x), hy = f2bf(y), hz = f2bf(z);
    const float fx = bf2f(hx), fy = bf2f(hy), fz = bf2f(hz);
    const unsigned short lx = f2bf(x - fx), ly = f2bf(y - fy), lz = f2bf(z - fz);
    const float t2 = x*x + y*y + z*z;
    const unsigned short t2h = f2bf(t2);
    const unsigned short t2l = f2bf(t2 - bf2f(t2h));

    union { unsigned short u[16]; int4 v[2]; } A;
    A.u[0] = f2bf(-2.f*fx); A.u[1] = f2bf(-2.f*fy); A.u[2] = f2bf(-2.f*fz);
    A.u[3] = f2bf(-2.f*bf2f(lx)); A.u[4] = f2bf(-2.f*bf2f(ly)); A.u[5] = f2bf(-2.f*bf2f(lz));
    A.u[6] = A.u[0]; A.u[7] = A.u[1]; A.u[8] = A.u[2];
    A.u[9] = A.u[3]; A.u[10] = A.u[4]; A.u[11] = A.u[5];
    A.u[12] = t2h; A.u[13] = t2l; A.u[14] = 0; A.u[15] = 0;

    // slot (1-c): dir0 (pred->target) uses A=target (c=1 -> slot 0)
    int4* ap = (int4*)(afmt + ((size_t)(1 - c) * 32768 + rem) * 16);
    ap[0] = A.v[0]; ap[1] = A.v[1];
}

// ---- K2 main: wave owns 128 preds (4 col-blocks), streams 1 chunk (32 tiles) ----
__global__ __launch_bounds__(256, 4) void chamfer_mfma(
    const float* __restrict__ pred, const float* __restrict__ target,
    const unsigned short* __restrict__ afmt,
    float* __restrict__ pmins)
{
    const int dirb = blockIdx.y;            // dir*4 + b
    const int dir  = dirb >> 2;
    const int b    = dirb & 3;
    const int chunk = blockIdx.z;
    const int wid  = threadIdx.x >> 6;
    const int lane = threadIdx.x & 63;
    const int half = lane >> 5;
    const int l31  = lane & 31;
    const int w    = blockIdx.x * 4 + wid;  // 0..63
    const int base = w * 128;               // first pred of this wave

    // build 4 B-frags in-register from raw coords
    const float* pc = ((dir == 0) ? pred : target) + (size_t)b * NPTS * 3;
    s8v bfrag[4];
#pragma unroll
    for (int q = 0; q < 4; ++q) {
        const float* sp = pc + (size_t)(base + q * 32 + l31) * 3;
        const float x = sp[0], y = sp[1], z = sp[2];
        const unsigned short hx = f2bf(x), hy = f2bf(y), hz = f2bf(z);
        const unsigned short lx = f2bf(x - bf2f(hx));
        const unsigned short ly = f2bf(y - bf2f(hy));
        const unsigned short lz = f2bf(z - bf2f(hz));
        union { unsigned short u[8]; s8v v; } F;
        if (half == 0) {
            F.u[0] = hx; F.u[1] = hy; F.u[2] = hz;
            F.u[3] = hx; F.u[4] = hy; F.u[5] = hz;
            F.u[6] = lx; F.u[7] = ly;
        } else {
            F.u[0] = lz; F.u[1] = lx; F.u[2] = ly; F.u[3] = lz;
            F.u[4] = 0x3F80; F.u[5] = 0x3F80; F.u[6] = 0; F.u[7] = 0;
        }
        bfrag[q] = F.v;
    }

    // stream this chunk's 32 A-tiles (512 ushorts each), rolling 4-reg prefetch
    const size_t cbase = ((size_t)dir * NB + b) * NPTS;
    const unsigned short* aptr = afmt + cbase * 16
        + (size_t)chunk * 32 * 512 + (l31 * 16 + half * 8);

    f16v zf = {};
    float mn[4] = {1e30f, 1e30f, 1e30f, 1e30f};

    s8v A0 = load16(aptr + 0*512), A1 = load16(aptr + 1*512),
        A2 = load16(aptr + 2*512), A3 = load16(aptr + 3*512);

#define TILE(AV, NEXTOFF) { \
    f16v c0 = __builtin_amdgcn_mfma_f32_32x32x16_bf16(AV, bfrag[0], zf, 0,0,0); \
    f16v c1 = __builtin_amdgcn_mfma_f32_32x32x16_bf16(AV, bfrag[1], zf, 0,0,0); \
    mn[0] = mintree(c0, mn[0]); \
    f16v c2 = __builtin_amdgcn_mfma_f32_32x32x16_bf16(AV, bfrag[2], zf, 0,0,0); \
    mn[1] = mintree(c1, mn[1]); \
    f16v c3 = __builtin_amdgcn_mfma_f32_32x32x16_bf16(AV, bfrag[3], zf, 0,0,0); \
    AV = load16(aptr + (NEXTOFF)); \
    mn[2] = mintree(c2, mn[2]); \
    mn[3] = mintree(c3, mn[3]); }

#pragma unroll
    for (int t = 0; t < 32; t += 4) {
        TILE(A0, (((t + 4) & 31) * 512))
        TILE(A1, (((t + 5) & 31) * 512))
        TILE(A2, (((t + 6) & 31) * 512))
        TILE(A3, (((t + 7) & 31) * 512))
    }
#undef TILE

    // merge row-halves: lane^32 holds the other 16 target-rows
#pragma unroll
    for (int q = 0; q < 4; ++q) mn[q] = fminf(mn[q], __shfl_xor(mn[q], 32));

    if (half == 0) {
        float* dst = pmins + ((size_t)dirb * CHUNKS + chunk) * NPTS + base + l31;
        dst[0]  = mn[0];
        dst[32] = mn[1];
        dst[64] = mn[2];
        dst[96] = mn[3];
    }
}

// ---- K3: merge chunks + |p|^2 + block partial sums + last-block final reduce ----
__global__ __launch_bounds__(256) void chamfer_mergefin(
    const float* __restrict__ pred, const float* __restrict__ target,
    const float* __restrict__ pmins, float* __restrict__ partials,
    int* __restrict__ done, float* __restrict__ out)
{
    const int tid = threadIdx.x;
    const int t = blockIdx.x * 256 + tid;           // 0..65535
    const int dirb = t >> 13;
    const int pr   = t & 8191;
    const int dir  = dirb >> 2;
    const int b    = dirb & 3;

    const float* mrow = pmins + (size_t)dirb * CHUNKS * NPTS + pr;
    float m = fminf(fminf(mrow[0*NPTS], mrow[1*NPTS]), mrow[2*NPTS]);
    m = fminf(fminf(m, mrow[3*NPTS]), mrow[4*NPTS]);
    m = fminf(fminf(m, mrow[5*NPTS]), mrow[6*NPTS]);
    m = fminf(m, mrow[7*NPTS]);

    const float* sp = ((dir == 0) ? pred : target) + ((size_t)b * NPTS + pr) * 3;
    const float p2 = sp[0]*sp[0] + sp[1]*sp[1] + sp[2]*sp[2];
    float v = (m + p2) * (1.0f / 32768.0f);

    __shared__ float s[256];
    __shared__ int lastFlag;
    s[tid] = v;
    __syncthreads();
    for (int wd = 128; wd > 0; wd >>= 1) {
        if (tid < wd) s[tid] += s[tid + wd];
        __syncthreads();
    }
    if (tid == 0) {
        __hip_atomic_store(&partials[blockIdx.x], s[0],
                           __ATOMIC_RELEASE, __HIP_MEMORY_SCOPE_AGENT);
        int prev = __hip_atomic_fetch_add(done, 1,
                           __ATOMIC_ACQ_REL, __HIP_MEMORY_SCOPE_AGENT);
        lastFlag = (prev == gridDim.x - 1);
    }
    __syncthreads();

    if (lastFlag) {   // exactly one block; sums fixed-order array -> deterministic
        float acc = __hip_atomic_load(&partials[tid],
                           __ATOMIC_ACQUIRE, __HIP_MEMORY_SCOPE_AGENT);
        s[tid] = acc;
        __syncthreads();
        for (int wd = 128; wd > 0; wd >>= 1) {
            if (tid < wd) s[tid] += s[tid + wd];
            __syncthreads();
        }
        if (tid == 0) out[0] = s[0];
    }
}

extern "C" void kernel_launch(void* const* d_in, const int* in_sizes, int n_in,
                              void* d_out, int out_size, void* d_ws, size_t ws_size,
                              hipStream_t stream)
{
    const float* pred   = (const float*)d_in[0];
    const float* target = (const float*)d_in[1];
    float* out = (float*)d_out;

    // ws: afmt 2 MB | pmins 2 MB | partials 1 KB | done counter
    unsigned short* afmt = (unsigned short*)d_ws;
    float* pmins    = (float*)((char*)d_ws + (size_t)2 * 1024 * 1024);
    float* partials = (float*)((char*)d_ws + (size_t)4 * 1024 * 1024);
    int*   done     = (int*)((char*)d_ws + (size_t)5 * 1024 * 1024);

    chamfer_prep<<<256, 256, 0, stream>>>(pred, target, afmt, done);

    dim3 grid(16, 8, CHUNKS);   // 1024 blocks, 4 waves each
    chamfer_mfma<<<grid, 256, 0, stream>>>(pred, target, afmt, pmins);

    chamfer_mergefin<<<256, 256, 0, stream>>>(pred, target, pmins, partials, done, out);
}